// Round 4
// baseline (11345.482 us; speedup 1.0000x reference)
//
#include <hip/hip_runtime.h>
#include <math.h>

#define B_    32
#define T_    2000
#define FIN_  80
#define H_    512
#define ROWS_ (B_ * T_)                 // 64000
#define BTH_  ((size_t)ROWS_ * H_)      // 32,768,000 floats
#define BH_   (B_ * H_)                 // 16384 floats

typedef unsigned long long u64;
typedef unsigned int u32;

// ---------------------------------------------------------------------------
// P1: proj = x @ W_proj + b ; LayerNorm(g1,b1) ; exact GELU.
// Output layout [t*32+b][512] (the scan's [T,B,H]). Written to d_out scratch
// (dead after P2; encoded overwrites it later).
// ---------------------------------------------------------------------------
__global__ __launch_bounds__(256) void proj_ln_gelu(
    const float* __restrict__ x, const float* __restrict__ Wp,
    const float* __restrict__ bp, const float* __restrict__ g1,
    const float* __restrict__ be1, float* __restrict__ out)
{
  __shared__ float xs[16][84];
  __shared__ float pr[16][512];
  __shared__ float mv[16][2];
  const int tid = threadIdx.x;
  const int r0 = blockIdx.x * 16;

  for (int f = tid; f < 320; f += 256) {
    int rr = f / 20, c4 = (f % 20) * 4;
    int r = r0 + rr; int b = r & 31; int t = r >> 5;
    float4 v = *(const float4*)(x + ((size_t)(b * T_ + t)) * FIN_ + c4);
    xs[rr][c4+0] = v.x; xs[rr][c4+1] = v.y; xs[rr][c4+2] = v.z; xs[rr][c4+3] = v.w;
  }
  __syncthreads();

  const int j = tid;
  float acc0[16], acc1[16];
#pragma unroll
  for (int rr = 0; rr < 16; ++rr) { acc0[rr] = 0.f; acc1[rr] = 0.f; }

  for (int k4 = 0; k4 < 20; ++k4) {
    float w0[4], w1[4];
#pragma unroll
    for (int i = 0; i < 4; ++i) {
      w0[i] = Wp[(k4*4+i)*H_ + j];
      w1[i] = Wp[(k4*4+i)*H_ + j + 256];
    }
#pragma unroll
    for (int rr = 0; rr < 16; ++rr) {
      float4 xv = *(const float4*)&xs[rr][k4*4];
      acc0[rr] += xv.x*w0[0] + xv.y*w0[1] + xv.z*w0[2] + xv.w*w0[3];
      acc1[rr] += xv.x*w1[0] + xv.y*w1[1] + xv.z*w1[2] + xv.w*w1[3];
    }
  }

  const float bj0 = bp[j], bj1 = bp[j+256];
#pragma unroll
  for (int rr = 0; rr < 16; ++rr) {
    pr[rr][j]     = acc0[rr] + bj0;
    pr[rr][j+256] = acc1[rr] + bj1;
  }
  __syncthreads();

  const int wv = tid >> 6, ln = tid & 63;
  for (int rr = wv*4; rr < wv*4+4; ++rr) {
    float s = 0.f, ss = 0.f;
#pragma unroll
    for (int q = 0; q < 8; ++q) { float v = pr[rr][ln + q*64]; s += v; ss += v*v; }
#pragma unroll
    for (int o = 32; o > 0; o >>= 1) { s += __shfl_xor(s, o, 64); ss += __shfl_xor(ss, o, 64); }
    if (ln == 0) {
      float m = s * (1.f/512.f);
      float var = ss * (1.f/512.f) - m*m;
      mv[rr][0] = m; mv[rr][1] = 1.f / sqrtf(var + 1e-5f);
    }
  }
  __syncthreads();

  const float ga0 = g1[j], ga1 = g1[j+256], bo0 = be1[j], bo1 = be1[j+256];
#pragma unroll
  for (int rr = 0; rr < 16; ++rr) {
    float m = mv[rr][0], rs = mv[rr][1];
    float v0 = (pr[rr][j]     - m) * rs * ga0 + bo0;
    float v1 = (pr[rr][j+256] - m) * rs * ga1 + bo1;
    v0 = v0 * 0.5f * (1.f + erff(v0 * 0.70710678118654752f));
    v1 = v1 * 0.5f * (1.f + erff(v1 * 0.70710678118654752f));
    size_t ro = (size_t)(r0 + rr) * H_;
    out[ro + j] = v0; out[ro + j + 256] = v1;
  }
}

// ---------------------------------------------------------------------------
// P2: xz0[64000,512] = GELUout @ W_in0 + b_rnn0, fp32.
// 128x128 tile, BK=16, 256 threads, 8x8 micro-tile, reg-prefetch pipeline.
// ---------------------------------------------------------------------------
__global__ __launch_bounds__(256) void gemm512(
    const float* __restrict__ A, const float* __restrict__ Bm,
    const float* __restrict__ bias, float* __restrict__ C)
{
  __shared__ float As[16][132];
  __shared__ float Bs[16][132];
  const int tid = threadIdx.x;
  const int n0 = blockIdx.x * 128;
  const int m0 = blockIdx.y * 128;
  const int tx = tid & 15, ty = tid >> 4;

  float acc[8][8];
#pragma unroll
  for (int i = 0; i < 8; ++i)
#pragma unroll
    for (int jj = 0; jj < 8; ++jj) acc[i][jj] = 0.f;

  float4 pa[2], pb[2];
#pragma unroll
  for (int i = 0; i < 2; ++i) {
    int f = i*256 + tid;
    int mm = f >> 2, kk4 = (f & 3) * 4;
    pa[i] = *(const float4*)(A + (size_t)(m0+mm)*H_ + kk4);
    int kk = f >> 5, nn4 = (f & 31) * 4;
    pb[i] = *(const float4*)(Bm + (size_t)kk*H_ + n0 + nn4);
  }

  for (int kt = 0; kt < 32; ++kt) {
    __syncthreads();
#pragma unroll
    for (int i = 0; i < 2; ++i) {
      int f = i*256 + tid;
      int mm = f >> 2, kk4 = (f & 3) * 4;
      As[kk4+0][mm] = pa[i].x; As[kk4+1][mm] = pa[i].y;
      As[kk4+2][mm] = pa[i].z; As[kk4+3][mm] = pa[i].w;
      int kk = f >> 5, nn4 = (f & 31) * 4;
      *(float4*)&Bs[kk][nn4] = pb[i];
    }
    __syncthreads();
    if (kt < 31) {
#pragma unroll
      for (int i = 0; i < 2; ++i) {
        int f = i*256 + tid;
        int mm = f >> 2, kk4 = (f & 3) * 4;
        pa[i] = *(const float4*)(A + (size_t)(m0+mm)*H_ + (kt+1)*16 + kk4);
        int kk = f >> 5, nn4 = (f & 31) * 4;
        pb[i] = *(const float4*)(Bm + (size_t)((kt+1)*16+kk)*H_ + n0 + nn4);
      }
    }
#pragma unroll
    for (int k = 0; k < 16; ++k) {
      float a[8], bb[8];
      *(float4*)(a+0) = *(const float4*)&As[k][ty*4];
      *(float4*)(a+4) = *(const float4*)&As[k][ty*4 + 64];
      *(float4*)(bb+0) = *(const float4*)&Bs[k][tx*4];
      *(float4*)(bb+4) = *(const float4*)&Bs[k][tx*4 + 64];
#pragma unroll
      for (int i = 0; i < 8; ++i)
#pragma unroll
        for (int jj = 0; jj < 8; ++jj) acc[i][jj] += a[i] * bb[jj];
    }
  }

  float4 bi0 = *(const float4*)(bias + n0 + tx*4);
  float4 bi1 = *(const float4*)(bias + n0 + tx*4 + 64);
#pragma unroll
  for (int i = 0; i < 8; ++i) {
    int m = m0 + ty*4 + (i & 3) + (i >> 2) * 64;
    float4 v0 = make_float4(acc[i][0]+bi0.x, acc[i][1]+bi0.y, acc[i][2]+bi0.z, acc[i][3]+bi0.w);
    float4 v1 = make_float4(acc[i][4]+bi1.x, acc[i][5]+bi1.y, acc[i][6]+bi1.z, acc[i][7]+bi1.w);
    *(float4*)(C + (size_t)m*H_ + n0 + tx*4)      = v0;
    *(float4*)(C + (size_t)m*H_ + n0 + tx*4 + 64) = v1;
  }
}

// ---------------------------------------------------------------------------
// Fused two-layer LTC scan, pipelined (layer-1 trails layer-0 by 1 step).
//
// Grid = 768 WGs x 512 threads:
//   blocks [0,256):   layer-0.  b = bid&31, s = bid>>5  (8 x 64-col slices)
//   blocks [256,768): layer-1.  idx=bid-256, b = idx>>4, s = idx&15 (16 x 32-col)
//
// h exchange: tag-embedded u64 = (step+1)<<32 | f32(h).  Each consumer thread
// polls exactly its own element (the poll IS the gather; single IF$ hop).
// Ping-pong parity + "publish implies prior-step fully read" => no overwrite
// hazard (proof: WG publishes t+1 only after gathering all of t; sibling j
// publishing t implies j finished reading t-1, the slot being overwritten).
//
// ys0 handoff: layer-0 overwrites xz0 in place in bufA via L2-bypass u64
// stores (packed float2), then vmcnt(0) drain, then sets its bit in
// ysflag[t][b] (atomic OR; consumer polls ==0xFF). Write-once per t => no
// backpressure. Layer-1 computes z1 = [ys0;h1] @ [W_in1;W_rec1] + b (K=1024).
//
// Output LN folded into layer-1: after gathering full h1[t-1], wave 0
// computes mean/var locally and writes encoded[b][t-1] directly.
//
// Deadlock-free at any residency: blocks dispatch in blockIdx order
// (resident set = prefix minus finished); layer-0 depends only on itself;
// layer-1 batch groups are 16 contiguous blocks depending only on themselves
// + layer-0 data; finished groups always free slots to extend the prefix.
// ---------------------------------------------------------------------------
__global__ __launch_bounds__(512, 6) void fused_scan(
    const float* __restrict__ Wrc0,   // W_rec[0]  [512][512]
    const float* __restrict__ Win1,   // W_in[1]   [512][512]
    const float* __restrict__ Wrc1,   // W_rec[1]  [512][512]
    const float* __restrict__ tra,    // tau_raw [2][512]
    const float* __restrict__ brn1,   // b_rnn[1] [512]
    const float* __restrict__ lng, const float* __restrict__ lnb,
    float* __restrict__ bufA,         // [T][B][512]: xz0 -> ys0 in place
    u64* __restrict__ h0tag,          // [2][B][512]
    u64* __restrict__ h1tag,          // [2][B][512]
    u32* __restrict__ ysflag,         // [T][B]
    float* __restrict__ enc,          // [B][T][512] final encoded (d_out)
    float* __restrict__ hid0,         // [B][512]
    float* __restrict__ hid1)         // [B][512]
{
  __shared__ float hl[1024];          // [0,512): ys0/h0 ; [512,1024): h1
  __shared__ float pt[2048];
  const int tid = threadIdx.x;

  if (blockIdx.x < 256) {
    // ================= layer 0 =================
    const int b  = blockIdx.x & 31;
    const int s  = blockIdx.x >> 5;
    const int j0 = s * 64;
    const int kg = tid >> 4;          // 32 k-groups of 16
    const int cq = tid & 15;          // 16 col-quads

    float wreg[64];
#pragma unroll
    for (int kk = 0; kk < 16; ++kk) {
      float4 wv = *(const float4*)(Wrc0 + (size_t)(kg*16 + kk)*H_ + j0 + cq*4);
      wreg[kk*4+0] = wv.x; wreg[kk*4+1] = wv.y; wreg[kk*4+2] = wv.z; wreg[kk*4+3] = wv.w;
    }
    float tau0 = 1.f, tau1 = 1.f;
    if (tid < 32) {
      float tr0 = tra[j0 + 2*tid], tr1 = tra[j0 + 2*tid + 1];
      tau0 = (tr0 > 20.f ? tr0 : log1pf(expf(tr0))) + 0.1f;
      tau1 = (tr1 > 20.f ? tr1 : log1pf(expf(tr1))) + 0.1f;
    }
    __syncthreads();

    for (int t = 0; t < T_; ++t) {
      // xz prefetch (plain cached load; cell overwritten later this step)
      float2 xzv = make_float2(0.f, 0.f);
      if (tid < 32)
        xzv = *(const float2*)(bufA + ((size_t)t * B_ + b) * H_ + j0 + 2*tid);

      // gather h0[t-1]: every thread polls its own tagged element
      if (t > 0) {
        const u64* rb = h0tag + ((size_t)((t + 1) & 1) * B_ + b) * H_;
        u64 v = __hip_atomic_load(rb + tid, __ATOMIC_RELAXED, __HIP_MEMORY_SCOPE_AGENT);
        while ((u32)(v >> 32) != (u32)t) {
          __builtin_amdgcn_s_sleep(1);
          v = __hip_atomic_load(rb + tid, __ATOMIC_RELAXED, __HIP_MEMORY_SCOPE_AGENT);
        }
        hl[tid] = __uint_as_float((u32)v);
      } else {
        hl[tid] = 0.f;
      }
      __syncthreads();   // B1: hl ready

      // matvec partials
      float hr[16];
#pragma unroll
      for (int q = 0; q < 4; ++q)
        *(float4*)(hr + q*4) = *(const float4*)(hl + kg*16 + q*4);
      float a0 = 0.f, a1 = 0.f, a2 = 0.f, a3 = 0.f;
#pragma unroll
      for (int kk = 0; kk < 16; ++kk) {
        float h = hr[kk];
        a0 += h * wreg[kk*4+0]; a1 += h * wreg[kk*4+1];
        a2 += h * wreg[kk*4+2]; a3 += h * wreg[kk*4+3];
      }
      *(float4*)&pt[kg*64 + cq*4] = make_float4(a0, a1, a2, a3);
      __syncthreads();   // B2

      // reduce + update + publish (wave 0; lanes split g-range, xor-combine)
      if (tid < 64) {
        int c2 = tid & 31;
        float s0 = 0.f, s1 = 0.f;
        for (int g = tid >> 5; g < 32; g += 2) {
          float2 p = *(const float2*)&pt[g*64 + c2*2];
          s0 += p.x; s1 += p.y;
        }
        s0 += __shfl_xor(s0, 32, 64);
        s1 += __shfl_xor(s1, 32, 64);
        if (tid < 32) {
          float z0 = xzv.x + s0, z1 = xzv.y + s1;
          float th0 = tanhf(z0), th1 = tanhf(z1);
          float h0v = hl[j0 + 2*tid], h1v = hl[j0 + 2*tid + 1];
          float hn0 = h0v + (th0 - h0v) / tau0;
          float hn1 = h1v + (th1 - h1v) / tau1;
          // publish tagged h (single-hop sync)
          u64* wb = h0tag + ((size_t)(t & 1) * B_ + b) * H_ + j0 + 2*tid;
          u64 tg = ((u64)(u32)(t + 1)) << 32;
          __hip_atomic_store(wb,     tg | __float_as_uint(hn0), __ATOMIC_RELAXED, __HIP_MEMORY_SCOPE_AGENT);
          __hip_atomic_store(wb + 1, tg | __float_as_uint(hn1), __ATOMIC_RELAXED, __HIP_MEMORY_SCOPE_AGENT);
          // ys0 data (in-place over xz cell), L2-bypass
          union { u64 u; float f[2]; } cv; cv.f[0] = hn0; cv.f[1] = hn1;
          u64* yw = (u64*)bufA + (((size_t)t * B_ + b) * H_ + j0) / 2 + tid;
          __hip_atomic_store(yw, cv.u, __ATOMIC_RELAXED, __HIP_MEMORY_SCOPE_AGENT);
          if (t == T_ - 1)
            *(float2*)(hid0 + b*H_ + j0 + 2*tid) = make_float2(hn0, hn1);
        }
      }
      if (tid == 0) {
        asm volatile("s_waitcnt vmcnt(0)" ::: "memory");   // ys data acked
        __hip_atomic_fetch_or(ysflag + (size_t)t * B_ + b, 1u << s,
                              __ATOMIC_RELAXED, __HIP_MEMORY_SCOPE_AGENT);
      }
      __syncthreads();   // protect hl until everyone is done reading
    }
  } else {
    // ================= layer 1 =================
    const int idx = blockIdx.x - 256;
    const int b  = idx >> 4;
    const int s  = idx & 15;
    const int j0 = s * 32;
    const int kg = tid >> 3;          // 64 k-groups of 16 (K = 1024)
    const int cq = tid & 7;           // 8 col-quads (32 cols)

    float wreg[64];
#pragma unroll
    for (int kk = 0; kk < 16; ++kk) {
      const float* base = (kg < 32)
          ? (Win1 + (size_t)(kg*16 + kk)*H_)
          : (Wrc1 + (size_t)((kg - 32)*16 + kk)*H_);
      float4 wv = *(const float4*)(base + j0 + cq*4);
      wreg[kk*4+0] = wv.x; wreg[kk*4+1] = wv.y; wreg[kk*4+2] = wv.z; wreg[kk*4+3] = wv.w;
    }
    float tauc = 1.f, bic = 0.f, gc = 1.f, bcc = 0.f;
    if (tid < 32) {
      float tr = tra[H_ + j0 + tid];
      tauc = (tr > 20.f ? tr : log1pf(expf(tr))) + 0.1f;
      bic = brn1[j0 + tid];
      gc = lng[j0 + tid];
      bcc = lnb[j0 + tid];
    }
    __syncthreads();

    for (int t = 0; t < T_; ++t) {
      // ---- ys0[t] readiness ----
      if (tid == 0) {
        while (__hip_atomic_load(ysflag + (size_t)t * B_ + b,
                                 __ATOMIC_RELAXED, __HIP_MEMORY_SCOPE_AGENT) != 0xFFu)
          __builtin_amdgcn_s_sleep(1);
      }
      __syncthreads();

      // issue h1 poll first (critical), overlap ys gather under its latency
      const u64* rb = h1tag + ((size_t)((t + 1) & 1) * B_ + b) * H_;
      u64 hv = 0;
      if (t > 0)
        hv = __hip_atomic_load(rb + tid, __ATOMIC_RELAXED, __HIP_MEMORY_SCOPE_AGENT);
      if (tid < 256) {
        u64 yv = __hip_atomic_load((const u64*)bufA + ((size_t)t * B_ + b) * (H_/2) + tid,
                                   __ATOMIC_RELAXED, __HIP_MEMORY_SCOPE_AGENT);
        union { u64 u; float f[2]; } cv; cv.u = yv;
        hl[2*tid]     = cv.f[0];
        hl[2*tid + 1] = cv.f[1];
      }
      if (t > 0) {
        while ((u32)(hv >> 32) != (u32)t) {
          __builtin_amdgcn_s_sleep(1);
          hv = __hip_atomic_load(rb + tid, __ATOMIC_RELAXED, __HIP_MEMORY_SCOPE_AGENT);
        }
        hl[512 + tid] = __uint_as_float((u32)hv);
      } else {
        hl[512 + tid] = 0.f;
      }
      __syncthreads();   // B1: hl[0..1024) ready

      // matvec over K=1024
      float hr[16];
#pragma unroll
      for (int q = 0; q < 4; ++q)
        *(float4*)(hr + q*4) = *(const float4*)(hl + kg*16 + q*4);
      float a0 = 0.f, a1 = 0.f, a2 = 0.f, a3 = 0.f;
#pragma unroll
      for (int kk = 0; kk < 16; ++kk) {
        float h = hr[kk];
        a0 += h * wreg[kk*4+0]; a1 += h * wreg[kk*4+1];
        a2 += h * wreg[kk*4+2]; a3 += h * wreg[kk*4+3];
      }
      *(float4*)&pt[kg*32 + cq*4] = make_float4(a0, a1, a2, a3);
      __syncthreads();   // B2

      if (tid < 64) {
        int c = tid & 31;
        float ps = 0.f;
        for (int g = tid >> 5; g < 64; g += 2) ps += pt[g*32 + c];
        ps += __shfl_xor(ps, 32, 64);
        float hn = 0.f, hold = 0.f;
        if (tid < 32) {
          float z = ps + bic;
          float th = tanhf(z);
          hold = hl[512 + j0 + tid];
          hn = hold + (th - hold) / tauc;
          u64* wb = h1tag + ((size_t)(t & 1) * B_ + b) * H_ + j0 + tid;
          __hip_atomic_store(wb, (((u64)(u32)(t + 1)) << 32) | __float_as_uint(hn),
                             __ATOMIC_RELAXED, __HIP_MEMORY_SCOPE_AGENT);
          if (t == T_ - 1) hid1[b*H_ + j0 + tid] = hn;
        }
        // folded output LN of h1[t-1] (hl h-half intact until next poll)
        if (t > 0) {
          float sm = 0.f, ss = 0.f;
#pragma unroll
          for (int q = 0; q < 8; ++q) {
            float v = hl[512 + tid*8 + q];
            sm += v; ss += v*v;
          }
#pragma unroll
          for (int o = 32; o > 0; o >>= 1) {
            sm += __shfl_xor(sm, o, 64);
            ss += __shfl_xor(ss, o, 64);
          }
          float m = sm * (1.f/512.f);
          float rs = 1.f / sqrtf(ss * (1.f/512.f) - m*m + 1e-5f);
          if (tid < 32)
            enc[((size_t)b * T_ + (t - 1)) * H_ + j0 + tid] = (hold - m) * rs * gc + bcc;
        }
      }
      __syncthreads();   // protect hl
    }

    // epilogue: encoded[b][T-1] = LN(h1[T-1])
    {
      const u64* rb = h1tag + ((size_t)((T_ - 1) & 1) * B_ + b) * H_;
      u64 v = __hip_atomic_load(rb + tid, __ATOMIC_RELAXED, __HIP_MEMORY_SCOPE_AGENT);
      while ((u32)(v >> 32) != (u32)T_) {
        __builtin_amdgcn_s_sleep(1);
        v = __hip_atomic_load(rb + tid, __ATOMIC_RELAXED, __HIP_MEMORY_SCOPE_AGENT);
      }
      hl[512 + tid] = __uint_as_float((u32)v);
      __syncthreads();
      if (tid < 64) {
        float sm = 0.f, ss = 0.f;
#pragma unroll
        for (int q = 0; q < 8; ++q) {
          float vv = hl[512 + tid*8 + q];
          sm += vv; ss += vv*vv;
        }
#pragma unroll
        for (int o = 32; o > 0; o >>= 1) {
          sm += __shfl_xor(sm, o, 64);
          ss += __shfl_xor(ss, o, 64);
        }
        float m = sm * (1.f/512.f);
        float rs = 1.f / sqrtf(ss * (1.f/512.f) - m*m + 1e-5f);
        if (tid < 32) {
          float hold = hl[512 + j0 + tid];
          enc[((size_t)b * T_ + (T_ - 1)) * H_ + j0 + tid] = (hold - m) * rs * gc + bcc;
        }
      }
    }
  }
}

// ---------------------------------------------------------------------------
extern "C" void kernel_launch(void* const* d_in, const int* in_sizes, int n_in,
                              void* d_out, int out_size, void* d_ws, size_t ws_size,
                              hipStream_t stream)
{
  (void)in_sizes; (void)n_in; (void)out_size;
  const float* x   = (const float*)d_in[0];
  const float* Wp  = (const float*)d_in[1];
  const float* bp  = (const float*)d_in[2];
  const float* g1  = (const float*)d_in[3];
  const float* be1 = (const float*)d_in[4];
  const float* Win = (const float*)d_in[5];   // [2][512][512]
  const float* Wrc = (const float*)d_in[6];   // [2][512][512]
  const float* brn = (const float*)d_in[7];   // [2][512]
  const float* tra = (const float*)d_in[8];   // [2][512]
  const float* gno = (const float*)d_in[9];
  const float* bno = (const float*)d_in[10];
  float* outp = (float*)d_out;

  // sync region: h0tag (256K) | h1tag (256K) | ysflag (256K) = 768 KB
  const size_t H0T_BYTES = (size_t)2 * B_ * H_ * 8;       // 262144
  const size_t YSF_BYTES = (size_t)T_ * B_ * 4;           // 256000
  const size_t SYNC_BYTES = 786432;
  const size_t BUFA_BYTES = BTH_ * 4;

  char* sync;
  float* bufA;
  if (ws_size >= SYNC_BYTES + BUFA_BYTES) {
    sync = (char*)d_ws;
    bufA = (float*)((char*)d_ws + SYNC_BYTES);
  } else {
    // fallback: x (20.5 MB) is dead after P1; use its head for sync bufs
    sync = (char*)d_in[0];
    bufA = (float*)d_ws;
  }
  u64* h0tag  = (u64*)sync;
  u64* h1tag  = (u64*)(sync + H0T_BYTES);
  u32* ysflag = (u32*)(sync + 2 * H0T_BYTES);
  (void)YSF_BYTES;

  // P1: x -> proj -> LN -> GELU, into d_out scratch ([T,B,H] rows; dead after P2)
  proj_ln_gelu<<<dim3(ROWS_/16), 256, 0, stream>>>(x, Wp, bp, g1, be1, outp);

  // P2: xz0 = GELUout @ W_in[0] + b_rnn[0] -> bufA
  gemm512<<<dim3(4, ROWS_/128), 256, 0, stream>>>(outp, Win, brn, bufA);

  // zero sync bufs (after P1 consumed x — required for the fallback layout)
  hipMemsetAsync(sync, 0, SYNC_BYTES, stream);

  // fused pipelined scan: layer-0 + layer-1 (+ folded output LN)
  fused_scan<<<768, 512, 0, stream>>>(
      Wrc, Win + H_*H_, Wrc + H_*H_, tra, brn + H_, gno, bno,
      bufA, h0tag, h1tag, ysflag,
      outp, outp + BTH_, outp + BTH_ + BH_);
}

// Round 5
// 9997.849 us; speedup vs baseline: 1.1348x; 1.1348x over previous
//
#include <hip/hip_runtime.h>
#include <math.h>

#define B_    32
#define T_    2000
#define FIN_  80
#define H_    512
#define ROWS_ (B_ * T_)                 // 64000
#define BTH_  ((size_t)ROWS_ * H_)      // 32,768,000 floats
#define BH_   (B_ * H_)                 // 16384 floats

typedef unsigned long long u64;
typedef unsigned int u32;

// ---------------------------------------------------------------------------
// P1: proj = x @ W_proj + b ; LayerNorm(g1,b1) ; exact GELU.
// Output layout [t*32+b][512] (the scan's [T,B,H]). Written to d_out scratch
// (dead after P2; encoded overwrites it later).
// ---------------------------------------------------------------------------
__global__ __launch_bounds__(256) void proj_ln_gelu(
    const float* __restrict__ x, const float* __restrict__ Wp,
    const float* __restrict__ bp, const float* __restrict__ g1,
    const float* __restrict__ be1, float* __restrict__ out)
{
  __shared__ float xs[16][84];
  __shared__ float pr[16][512];
  __shared__ float mv[16][2];
  const int tid = threadIdx.x;
  const int r0 = blockIdx.x * 16;

  for (int f = tid; f < 320; f += 256) {
    int rr = f / 20, c4 = (f % 20) * 4;
    int r = r0 + rr; int b = r & 31; int t = r >> 5;
    float4 v = *(const float4*)(x + ((size_t)(b * T_ + t)) * FIN_ + c4);
    xs[rr][c4+0] = v.x; xs[rr][c4+1] = v.y; xs[rr][c4+2] = v.z; xs[rr][c4+3] = v.w;
  }
  __syncthreads();

  const int j = tid;
  float acc0[16], acc1[16];
#pragma unroll
  for (int rr = 0; rr < 16; ++rr) { acc0[rr] = 0.f; acc1[rr] = 0.f; }

  for (int k4 = 0; k4 < 20; ++k4) {
    float w0[4], w1[4];
#pragma unroll
    for (int i = 0; i < 4; ++i) {
      w0[i] = Wp[(k4*4+i)*H_ + j];
      w1[i] = Wp[(k4*4+i)*H_ + j + 256];
    }
#pragma unroll
    for (int rr = 0; rr < 16; ++rr) {
      float4 xv = *(const float4*)&xs[rr][k4*4];
      acc0[rr] += xv.x*w0[0] + xv.y*w0[1] + xv.z*w0[2] + xv.w*w0[3];
      acc1[rr] += xv.x*w1[0] + xv.y*w1[1] + xv.z*w1[2] + xv.w*w1[3];
    }
  }

  const float bj0 = bp[j], bj1 = bp[j+256];
#pragma unroll
  for (int rr = 0; rr < 16; ++rr) {
    pr[rr][j]     = acc0[rr] + bj0;
    pr[rr][j+256] = acc1[rr] + bj1;
  }
  __syncthreads();

  const int wv = tid >> 6, ln = tid & 63;
  for (int rr = wv*4; rr < wv*4+4; ++rr) {
    float s = 0.f, ss = 0.f;
#pragma unroll
    for (int q = 0; q < 8; ++q) { float v = pr[rr][ln + q*64]; s += v; ss += v*v; }
#pragma unroll
    for (int o = 32; o > 0; o >>= 1) { s += __shfl_xor(s, o, 64); ss += __shfl_xor(ss, o, 64); }
    if (ln == 0) {
      float m = s * (1.f/512.f);
      float var = ss * (1.f/512.f) - m*m;
      mv[rr][0] = m; mv[rr][1] = 1.f / sqrtf(var + 1e-5f);
    }
  }
  __syncthreads();

  const float ga0 = g1[j], ga1 = g1[j+256], bo0 = be1[j], bo1 = be1[j+256];
#pragma unroll
  for (int rr = 0; rr < 16; ++rr) {
    float m = mv[rr][0], rs = mv[rr][1];
    float v0 = (pr[rr][j]     - m) * rs * ga0 + bo0;
    float v1 = (pr[rr][j+256] - m) * rs * ga1 + bo1;
    v0 = v0 * 0.5f * (1.f + erff(v0 * 0.70710678118654752f));
    v1 = v1 * 0.5f * (1.f + erff(v1 * 0.70710678118654752f));
    size_t ro = (size_t)(r0 + rr) * H_;
    out[ro + j] = v0; out[ro + j + 256] = v1;
  }
}

// ---------------------------------------------------------------------------
// P2: xz0[64000,512] = GELUout @ W_in0 + b_rnn0, fp32.
// 128x128 tile, BK=16, 256 threads, 8x8 micro-tile, reg-prefetch pipeline.
// ---------------------------------------------------------------------------
__global__ __launch_bounds__(256) void gemm512(
    const float* __restrict__ A, const float* __restrict__ Bm,
    const float* __restrict__ bias, float* __restrict__ C)
{
  __shared__ float As[16][132];
  __shared__ float Bs[16][132];
  const int tid = threadIdx.x;
  const int n0 = blockIdx.x * 128;
  const int m0 = blockIdx.y * 128;
  const int tx = tid & 15, ty = tid >> 4;

  float acc[8][8];
#pragma unroll
  for (int i = 0; i < 8; ++i)
#pragma unroll
    for (int jj = 0; jj < 8; ++jj) acc[i][jj] = 0.f;

  float4 pa[2], pb[2];
#pragma unroll
  for (int i = 0; i < 2; ++i) {
    int f = i*256 + tid;
    int mm = f >> 2, kk4 = (f & 3) * 4;
    pa[i] = *(const float4*)(A + (size_t)(m0+mm)*H_ + kk4);
    int kk = f >> 5, nn4 = (f & 31) * 4;
    pb[i] = *(const float4*)(Bm + (size_t)kk*H_ + n0 + nn4);
  }

  for (int kt = 0; kt < 32; ++kt) {
    __syncthreads();
#pragma unroll
    for (int i = 0; i < 2; ++i) {
      int f = i*256 + tid;
      int mm = f >> 2, kk4 = (f & 3) * 4;
      As[kk4+0][mm] = pa[i].x; As[kk4+1][mm] = pa[i].y;
      As[kk4+2][mm] = pa[i].z; As[kk4+3][mm] = pa[i].w;
      int kk = f >> 5, nn4 = (f & 31) * 4;
      *(float4*)&Bs[kk][nn4] = pb[i];
    }
    __syncthreads();
    if (kt < 31) {
#pragma unroll
      for (int i = 0; i < 2; ++i) {
        int f = i*256 + tid;
        int mm = f >> 2, kk4 = (f & 3) * 4;
        pa[i] = *(const float4*)(A + (size_t)(m0+mm)*H_ + (kt+1)*16 + kk4);
        int kk = f >> 5, nn4 = (f & 31) * 4;
        pb[i] = *(const float4*)(Bm + (size_t)((kt+1)*16+kk)*H_ + n0 + nn4);
      }
    }
#pragma unroll
    for (int k = 0; k < 16; ++k) {
      float a[8], bb[8];
      *(float4*)(a+0) = *(const float4*)&As[k][ty*4];
      *(float4*)(a+4) = *(const float4*)&As[k][ty*4 + 64];
      *(float4*)(bb+0) = *(const float4*)&Bs[k][tx*4];
      *(float4*)(bb+4) = *(const float4*)&Bs[k][tx*4 + 64];
#pragma unroll
      for (int i = 0; i < 8; ++i)
#pragma unroll
        for (int jj = 0; jj < 8; ++jj) acc[i][jj] += a[i] * bb[jj];
    }
  }

  float4 bi0 = *(const float4*)(bias + n0 + tx*4);
  float4 bi1 = *(const float4*)(bias + n0 + tx*4 + 64);
#pragma unroll
  for (int i = 0; i < 8; ++i) {
    int m = m0 + ty*4 + (i & 3) + (i >> 2) * 64;
    float4 v0 = make_float4(acc[i][0]+bi0.x, acc[i][1]+bi0.y, acc[i][2]+bi0.z, acc[i][3]+bi0.w);
    float4 v1 = make_float4(acc[i][4]+bi1.x, acc[i][5]+bi1.y, acc[i][6]+bi1.z, acc[i][7]+bi1.w);
    *(float4*)(C + (size_t)m*H_ + n0 + tx*4)      = v0;
    *(float4*)(C + (size_t)m*H_ + n0 + tx*4 + 64) = v1;
  }
}

// ---------------------------------------------------------------------------
// Fused two-layer LTC scan, pipelined (layer-1 trails layer-0 by 1 step).
//
// Grid = 768 WGs x 512 threads:
//   blocks [0,256):   layer-0.  b = bid&31, s = bid>>5  (8 x 64-col slices)
//   blocks [256,768): layer-1.  idx=bid-256, b = idx>>4, s = idx&15 (16 x 32-col)
//
// NOTE on launch bounds: plain (512) — NO min-waves clause. Round-4 used
// (512,6), which capped the VGPR budget at ~85 and made the allocator spill
// wreg[64] to scratch (VGPR_Count=40, FETCH +1.6GB, 2.4x slowdown). The
// weight-in-registers design NEEDS ~80-100 VGPRs; occupancy is secondary.
// Deadlock-freedom does not need >1 block/CU: layer-0's 8 siblings all lie
// in blocks [0,256) (resident even at 1 block/CU), layer-0 never waits on
// layer-1 (ysflag is write-once, no backpressure), and layer-1 groups are
// 16 contiguous blocks served by in-order prefix dispatch.
//
// h exchange: tag-embedded u64 = (step+1)<<32 | f32(h). Each consumer thread
// polls exactly its own element (the poll IS the gather; single IF$ hop).
// Ping-pong parity + "publish implies prior-step fully read" => no overwrite
// hazard.
// ---------------------------------------------------------------------------
__global__ __launch_bounds__(512) void fused_scan(
    const float* __restrict__ Wrc0,   // W_rec[0]  [512][512]
    const float* __restrict__ Win1,   // W_in[1]   [512][512]
    const float* __restrict__ Wrc1,   // W_rec[1]  [512][512]
    const float* __restrict__ tra,    // tau_raw [2][512]
    const float* __restrict__ brn1,   // b_rnn[1] [512]
    const float* __restrict__ lng, const float* __restrict__ lnb,
    float* __restrict__ bufA,         // [T][B][512]: xz0 -> ys0 in place
    u64* __restrict__ h0tag,          // [2][B][512]
    u64* __restrict__ h1tag,          // [2][B][512]
    u32* __restrict__ ysflag,         // [T][B]
    float* __restrict__ enc,          // [B][T][512] final encoded (d_out)
    float* __restrict__ hid0,         // [B][512]
    float* __restrict__ hid1)         // [B][512]
{
  __shared__ float hl[1024];          // [0,512): ys0/h0 ; [512,1024): h1
  __shared__ float pt[2048];
  const int tid = threadIdx.x;

  if (blockIdx.x < 256) {
    // ================= layer 0 =================
    const int b  = blockIdx.x & 31;
    const int s  = blockIdx.x >> 5;
    const int j0 = s * 64;
    const int kg = tid >> 4;          // 32 k-groups of 16
    const int cq = tid & 15;          // 16 col-quads

    float wreg[64];
    {
      const float* wsrc = Wrc0 + (size_t)(kg * 16) * H_ + j0 + cq * 4;
#pragma unroll
      for (int kk = 0; kk < 16; ++kk) {
        float4 wv = *(const float4*)(wsrc + (size_t)kk * H_);
        wreg[kk*4+0] = wv.x; wreg[kk*4+1] = wv.y; wreg[kk*4+2] = wv.z; wreg[kk*4+3] = wv.w;
      }
    }
    float tau0 = 1.f, tau1 = 1.f;
    if (tid < 32) {
      float tr0 = tra[j0 + 2*tid], tr1 = tra[j0 + 2*tid + 1];
      tau0 = (tr0 > 20.f ? tr0 : log1pf(expf(tr0))) + 0.1f;
      tau1 = (tr1 > 20.f ? tr1 : log1pf(expf(tr1))) + 0.1f;
    }
    __syncthreads();

    for (int t = 0; t < T_; ++t) {
      // xz prefetch (plain cached load; cell overwritten later this step)
      float2 xzv = make_float2(0.f, 0.f);
      if (tid < 32)
        xzv = *(const float2*)(bufA + ((size_t)t * B_ + b) * H_ + j0 + 2*tid);

      // gather h0[t-1]: every thread polls its own tagged element
      if (t > 0) {
        const u64* rb = h0tag + ((size_t)((t + 1) & 1) * B_ + b) * H_;
        u64 v = __hip_atomic_load(rb + tid, __ATOMIC_RELAXED, __HIP_MEMORY_SCOPE_AGENT);
        while ((u32)(v >> 32) != (u32)t) {
          __builtin_amdgcn_s_sleep(1);
          v = __hip_atomic_load(rb + tid, __ATOMIC_RELAXED, __HIP_MEMORY_SCOPE_AGENT);
        }
        hl[tid] = __uint_as_float((u32)v);
      } else {
        hl[tid] = 0.f;
      }
      __syncthreads();   // B1: hl ready

      // matvec partials
      float hr[16];
#pragma unroll
      for (int q = 0; q < 4; ++q)
        *(float4*)(hr + q*4) = *(const float4*)(hl + kg*16 + q*4);
      float a0 = 0.f, a1 = 0.f, a2 = 0.f, a3 = 0.f;
#pragma unroll
      for (int kk = 0; kk < 16; ++kk) {
        float h = hr[kk];
        a0 += h * wreg[kk*4+0]; a1 += h * wreg[kk*4+1];
        a2 += h * wreg[kk*4+2]; a3 += h * wreg[kk*4+3];
      }
      *(float4*)&pt[kg*64 + cq*4] = make_float4(a0, a1, a2, a3);
      __syncthreads();   // B2

      // reduce + update + publish (wave 0; lanes split g-range, xor-combine)
      if (tid < 64) {
        int c2 = tid & 31;
        float s0 = 0.f, s1 = 0.f;
        for (int g = tid >> 5; g < 32; g += 2) {
          float2 p = *(const float2*)&pt[g*64 + c2*2];
          s0 += p.x; s1 += p.y;
        }
        s0 += __shfl_xor(s0, 32, 64);
        s1 += __shfl_xor(s1, 32, 64);
        if (tid < 32) {
          float z0 = xzv.x + s0, z1 = xzv.y + s1;
          float th0 = tanhf(z0), th1 = tanhf(z1);
          float h0v = hl[j0 + 2*tid], h1v = hl[j0 + 2*tid + 1];
          float hn0 = h0v + (th0 - h0v) / tau0;
          float hn1 = h1v + (th1 - h1v) / tau1;
          // publish tagged h (single-hop sync)
          u64* wb = h0tag + ((size_t)(t & 1) * B_ + b) * H_ + j0 + 2*tid;
          u64 tg = ((u64)(u32)(t + 1)) << 32;
          __hip_atomic_store(wb,     tg | __float_as_uint(hn0), __ATOMIC_RELAXED, __HIP_MEMORY_SCOPE_AGENT);
          __hip_atomic_store(wb + 1, tg | __float_as_uint(hn1), __ATOMIC_RELAXED, __HIP_MEMORY_SCOPE_AGENT);
          // ys0 data (in-place over xz cell), L2-bypass
          union { u64 u; float f[2]; } cv; cv.f[0] = hn0; cv.f[1] = hn1;
          u64* yw = (u64*)bufA + (((size_t)t * B_ + b) * H_ + j0) / 2 + tid;
          __hip_atomic_store(yw, cv.u, __ATOMIC_RELAXED, __HIP_MEMORY_SCOPE_AGENT);
          if (t == T_ - 1)
            *(float2*)(hid0 + b*H_ + j0 + 2*tid) = make_float2(hn0, hn1);
        }
      }
      if (tid == 0) {
        asm volatile("s_waitcnt vmcnt(0)" ::: "memory");   // ys data acked
        __hip_atomic_fetch_or(ysflag + (size_t)t * B_ + b, 1u << s,
                              __ATOMIC_RELAXED, __HIP_MEMORY_SCOPE_AGENT);
      }
      __syncthreads();   // protect hl until everyone is done reading
    }
  } else {
    // ================= layer 1 =================
    const int idx = blockIdx.x - 256;
    const int b  = idx >> 4;
    const int s  = idx & 15;
    const int j0 = s * 32;
    const int kg = tid >> 3;          // 64 k-groups of 16 (K = 1024)
    const int cq = tid & 7;           // 8 col-quads (32 cols)

    float wreg[64];
    {
      const float* wsrc = (kg < 32)
          ? (Win1 + (size_t)(kg * 16) * H_ + j0 + cq * 4)
          : (Wrc1 + (size_t)((kg - 32) * 16) * H_ + j0 + cq * 4);
#pragma unroll
      for (int kk = 0; kk < 16; ++kk) {
        float4 wv = *(const float4*)(wsrc + (size_t)kk * H_);
        wreg[kk*4+0] = wv.x; wreg[kk*4+1] = wv.y; wreg[kk*4+2] = wv.z; wreg[kk*4+3] = wv.w;
      }
    }
    float tauc = 1.f, bic = 0.f, gc = 1.f, bcc = 0.f;
    if (tid < 32) {
      float tr = tra[H_ + j0 + tid];
      tauc = (tr > 20.f ? tr : log1pf(expf(tr))) + 0.1f;
      bic = brn1[j0 + tid];
      gc = lng[j0 + tid];
      bcc = lnb[j0 + tid];
    }
    __syncthreads();

    for (int t = 0; t < T_; ++t) {
      // ---- ys0[t] readiness ----
      if (tid == 0) {
        while (__hip_atomic_load(ysflag + (size_t)t * B_ + b,
                                 __ATOMIC_RELAXED, __HIP_MEMORY_SCOPE_AGENT) != 0xFFu)
          __builtin_amdgcn_s_sleep(1);
      }
      __syncthreads();

      // issue h1 poll first (critical), overlap ys gather under its latency
      const u64* rb = h1tag + ((size_t)((t + 1) & 1) * B_ + b) * H_;
      u64 hv = 0;
      if (t > 0)
        hv = __hip_atomic_load(rb + tid, __ATOMIC_RELAXED, __HIP_MEMORY_SCOPE_AGENT);
      if (tid < 256) {
        u64 yv = __hip_atomic_load((const u64*)bufA + ((size_t)t * B_ + b) * (H_/2) + tid,
                                   __ATOMIC_RELAXED, __HIP_MEMORY_SCOPE_AGENT);
        union { u64 u; float f[2]; } cv; cv.u = yv;
        hl[2*tid]     = cv.f[0];
        hl[2*tid + 1] = cv.f[1];
      }
      if (t > 0) {
        while ((u32)(hv >> 32) != (u32)t) {
          __builtin_amdgcn_s_sleep(1);
          hv = __hip_atomic_load(rb + tid, __ATOMIC_RELAXED, __HIP_MEMORY_SCOPE_AGENT);
        }
        hl[512 + tid] = __uint_as_float((u32)hv);
      } else {
        hl[512 + tid] = 0.f;
      }
      __syncthreads();   // B1: hl[0..1024) ready

      // matvec over K=1024
      float hr[16];
#pragma unroll
      for (int q = 0; q < 4; ++q)
        *(float4*)(hr + q*4) = *(const float4*)(hl + kg*16 + q*4);
      float a0 = 0.f, a1 = 0.f, a2 = 0.f, a3 = 0.f;
#pragma unroll
      for (int kk = 0; kk < 16; ++kk) {
        float h = hr[kk];
        a0 += h * wreg[kk*4+0]; a1 += h * wreg[kk*4+1];
        a2 += h * wreg[kk*4+2]; a3 += h * wreg[kk*4+3];
      }
      *(float4*)&pt[kg*32 + cq*4] = make_float4(a0, a1, a2, a3);
      __syncthreads();   // B2

      if (tid < 64) {
        int c = tid & 31;
        float ps = 0.f;
        for (int g = tid >> 5; g < 64; g += 2) ps += pt[g*32 + c];
        ps += __shfl_xor(ps, 32, 64);
        float hn = 0.f, hold = 0.f;
        if (tid < 32) {
          float z = ps + bic;
          float th = tanhf(z);
          hold = hl[512 + j0 + tid];
          hn = hold + (th - hold) / tauc;
          u64* wb = h1tag + ((size_t)(t & 1) * B_ + b) * H_ + j0 + tid;
          __hip_atomic_store(wb, (((u64)(u32)(t + 1)) << 32) | __float_as_uint(hn),
                             __ATOMIC_RELAXED, __HIP_MEMORY_SCOPE_AGENT);
          if (t == T_ - 1) hid1[b*H_ + j0 + tid] = hn;
        }
        // folded output LN of h1[t-1] (hl h-half intact until next poll)
        if (t > 0) {
          float sm = 0.f, ss = 0.f;
#pragma unroll
          for (int q = 0; q < 8; ++q) {
            float v = hl[512 + tid*8 + q];
            sm += v; ss += v*v;
          }
#pragma unroll
          for (int o = 32; o > 0; o >>= 1) {
            sm += __shfl_xor(sm, o, 64);
            ss += __shfl_xor(ss, o, 64);
          }
          float m = sm * (1.f/512.f);
          float rs = 1.f / sqrtf(ss * (1.f/512.f) - m*m + 1e-5f);
          if (tid < 32)
            enc[((size_t)b * T_ + (t - 1)) * H_ + j0 + tid] = (hold - m) * rs * gc + bcc;
        }
      }
      __syncthreads();   // protect hl
    }

    // epilogue: encoded[b][T-1] = LN(h1[T-1])
    {
      const u64* rb = h1tag + ((size_t)((T_ - 1) & 1) * B_ + b) * H_;
      u64 v = __hip_atomic_load(rb + tid, __ATOMIC_RELAXED, __HIP_MEMORY_SCOPE_AGENT);
      while ((u32)(v >> 32) != (u32)T_) {
        __builtin_amdgcn_s_sleep(1);
        v = __hip_atomic_load(rb + tid, __ATOMIC_RELAXED, __HIP_MEMORY_SCOPE_AGENT);
      }
      hl[512 + tid] = __uint_as_float((u32)v);
      __syncthreads();
      if (tid < 64) {
        float sm = 0.f, ss = 0.f;
#pragma unroll
        for (int q = 0; q < 8; ++q) {
          float vv = hl[512 + tid*8 + q];
          sm += vv; ss += vv*vv;
        }
#pragma unroll
        for (int o = 32; o > 0; o >>= 1) {
          sm += __shfl_xor(sm, o, 64);
          ss += __shfl_xor(ss, o, 64);
        }
        float m = sm * (1.f/512.f);
        float rs = 1.f / sqrtf(ss * (1.f/512.f) - m*m + 1e-5f);
        if (tid < 32) {
          float hold = hl[512 + j0 + tid];
          enc[((size_t)b * T_ + (T_ - 1)) * H_ + j0 + tid] = (hold - m) * rs * gc + bcc;
        }
      }
    }
  }
}

// ---------------------------------------------------------------------------
extern "C" void kernel_launch(void* const* d_in, const int* in_sizes, int n_in,
                              void* d_out, int out_size, void* d_ws, size_t ws_size,
                              hipStream_t stream)
{
  (void)in_sizes; (void)n_in; (void)out_size;
  const float* x   = (const float*)d_in[0];
  const float* Wp  = (const float*)d_in[1];
  const float* bp  = (const float*)d_in[2];
  const float* g1  = (const float*)d_in[3];
  const float* be1 = (const float*)d_in[4];
  const float* Win = (const float*)d_in[5];   // [2][512][512]
  const float* Wrc = (const float*)d_in[6];   // [2][512][512]
  const float* brn = (const float*)d_in[7];   // [2][512]
  const float* tra = (const float*)d_in[8];   // [2][512]
  const float* gno = (const float*)d_in[9];
  const float* bno = (const float*)d_in[10];
  float* outp = (float*)d_out;

  // sync region: h0tag (256K) | h1tag (256K) | ysflag (256K) = 768 KB
  const size_t H0T_BYTES = (size_t)2 * B_ * H_ * 8;       // 262144
  const size_t SYNC_BYTES = 786432;
  const size_t BUFA_BYTES = BTH_ * 4;

  char* sync;
  float* bufA;
  if (ws_size >= SYNC_BYTES + BUFA_BYTES) {
    sync = (char*)d_ws;
    bufA = (float*)((char*)d_ws + SYNC_BYTES);
  } else {
    // fallback: x (20.5 MB) is dead after P1; use its head for sync bufs
    sync = (char*)d_in[0];
    bufA = (float*)d_ws;
  }
  u64* h0tag  = (u64*)sync;
  u64* h1tag  = (u64*)(sync + H0T_BYTES);
  u32* ysflag = (u32*)(sync + 2 * H0T_BYTES);

  // P1: x -> proj -> LN -> GELU, into d_out scratch ([T,B,H] rows; dead after P2)
  proj_ln_gelu<<<dim3(ROWS_/16), 256, 0, stream>>>(x, Wp, bp, g1, be1, outp);

  // P2: xz0 = GELUout @ W_in[0] + b_rnn[0] -> bufA
  gemm512<<<dim3(4, ROWS_/128), 256, 0, stream>>>(outp, Win, brn, bufA);

  // zero sync bufs (after P1 consumed x — required for the fallback layout)
  hipMemsetAsync(sync, 0, SYNC_BYTES, stream);

  // fused pipelined scan: layer-0 + layer-1 (+ folded output LN)
  fused_scan<<<768, 512, 0, stream>>>(
      Wrc, Win + H_*H_, Wrc + H_*H_, tra, brn + H_, gno, bno,
      bufA, h0tag, h1tag, ysflag,
      outp, outp + BTH_, outp + BTH_ + BH_);
}